// Round 3
// baseline (1016.946 us; speedup 1.0000x reference)
//
#include <hip/hip_runtime.h>
#include <hip/hip_bf16.h>

#define N_NODES 10000
#define N_EDGES 640000
#define HD 128          // NUM_HEADS * OUT_DIM
#define NH 8
#define TPAD 136        // LDS row pad: 272B stride -> 2-way bank alias (free)

typedef __attribute__((ext_vector_type(4))) float floatx4;
typedef __attribute__((ext_vector_type(8))) __bf16 bf16x8;

__device__ __forceinline__ float b2f(unsigned short u) {
    union { unsigned int i; float f; } x;
    x.i = ((unsigned int)u) << 16;
    return x.f;
}
__device__ __forceinline__ unsigned short f2b(float f) {   // RNE bf16
    union { float f; unsigned int i; } x; x.f = f;
    unsigned int r = x.i + 0x7FFF + ((x.i >> 16) & 1);
    return (unsigned short)(r >> 16);
}

template<bool F32>
__device__ __forceinline__ float ld1(const void* p, size_t i) {
    if (F32) return ((const float*)p)[i];
    return b2f(((const unsigned short*)p)[i]);
}
template<bool F32>
__device__ __forceinline__ void ld8(const void* p, size_t i, float* out) {
    if (F32) {
        floatx4 a = *(const floatx4*)((const float*)p + i);
        floatx4 b = *(const floatx4*)((const float*)p + i + 4);
        out[0]=a[0]; out[1]=a[1]; out[2]=a[2]; out[3]=a[3];
        out[4]=b[0]; out[5]=b[1]; out[6]=b[2]; out[7]=b[3];
    } else {
        uint4 u = *(const uint4*)((const unsigned short*)p + i);
        const unsigned short* s = (const unsigned short*)&u;
        #pragma unroll
        for (int j = 0; j < 8; ++j) out[j] = b2f(s[j]);
    }
}
// load 8 elems -> packed bf16 (uint4)
template<bool F32>
__device__ __forceinline__ uint4 ld8b(const void* p, size_t i) {
    if (F32) {
        float f[8]; ld8<true>(p, i, f);
        union { unsigned short s[8]; uint4 u; } r;
        #pragma unroll
        for (int j = 0; j < 8; ++j) r.s[j] = f2b(f[j]);
        return r.u;
    }
    return *(const uint4*)((const unsigned short*)p + i);
}

// ---------------- Kernel 0: dtype sniff (1 block) ----------------
// Genuine bf16 normal data never has exponent field >= 0x8F (|x|>=2^16);
// fp32 low half-words have random exponent bits -> ~44% exceed.
__global__ void k_sniff(const unsigned short* __restrict__ h,
                        int* __restrict__ wcnt, int* __restrict__ flag) {
    int t = threadIdx.x;
    int w = 0;
    #pragma unroll
    for (int j = 0; j < 16; ++j) {
        unsigned short u = h[t * 16 + j];
        int ex = (u >> 7) & 0xFF;
        if (ex >= 0x8F) ++w;
    }
    atomicAdd(wcnt, w);
    __threadfence();
    __syncthreads();
    if (t == 0) {
        int c = atomicAdd(wcnt, 0);
        *flag = (c > 64) ? 1 : 0;   // 1 => inputs (and output) are fp32
    }
}

// ---------------- Kernel 1: Q/K/V projections (Q pre-scaled by 0.25) ----
template<bool F32>
__device__ __forceinline__ void qkv_body(
    float (*hs)[HD],
    const void* __restrict__ h,
    const void* __restrict__ Wq, const void* __restrict__ bq,
    const void* __restrict__ Wk, const void* __restrict__ bk,
    const void* __restrict__ Wv, const void* __restrict__ bv,
    float* __restrict__ Qs, float* __restrict__ Kg, float* __restrict__ Vg)
{
    const int n0 = blockIdx.x * 8;
    const int d = threadIdx.x;
    #pragma unroll
    for (int r = 0; r < 8; ++r)
        hs[r][d] = ld1<F32>(h, (size_t)(n0 + r) * HD + d);
    __syncthreads();

    float aq[8], ak[8], av[8];
    #pragma unroll
    for (int i = 0; i < 8; ++i) { aq[i] = 0.f; ak[i] = 0.f; av[i] = 0.f; }

    for (int c = 0; c < 16; ++c) {
        float wqf[8], wkf[8], wvf[8];
        ld8<F32>(Wq, (size_t)d * HD + c * 8, wqf);
        ld8<F32>(Wk, (size_t)d * HD + c * 8, wkf);
        ld8<F32>(Wv, (size_t)d * HD + c * 8, wvf);
        #pragma unroll
        for (int n = 0; n < 8; ++n) {
            #pragma unroll
            for (int j = 0; j < 8; ++j) {
                float hv = hs[n][c * 8 + j];   // broadcast (conflict-free)
                aq[n] += wqf[j] * hv;
                ak[n] += wkf[j] * hv;
                av[n] += wvf[j] * hv;
            }
        }
    }
    const float bqd = ld1<F32>(bq, d), bkd = ld1<F32>(bk, d), bvd = ld1<F32>(bv, d);
    #pragma unroll
    for (int n = 0; n < 8; ++n) {
        size_t o = (size_t)(n0 + n) * HD + d;
        Qs[o] = 0.25f * (aq[n] + bqd);   // fold 1/sqrt(16)
        Kg[o] = ak[n] + bkd;
        Vg[o] = av[n] + bvd;
    }
}

__global__ __launch_bounds__(128) void k_qkv(
    const void* h, const void* Wq, const void* bq, const void* Wk, const void* bk,
    const void* Wv, const void* bv,
    float* Qs, float* Kg, float* Vg, const int* flag)
{
    __shared__ float hs[8][HD];
    if (*flag) qkv_body<true >(hs, h, Wq, bq, Wk, bk, Wv, bv, Qs, Kg, Vg);
    else       qkv_body<false>(hs, h, Wq, bq, Wk, bk, Wv, bv, Qs, Kg, Vg);
}

// ---------------- Kernel 2a: histogram of dst ----
__global__ void k_hist(const int* __restrict__ dst, int* __restrict__ cnt) {
    int i = blockIdx.x * blockDim.x + threadIdx.x;
    if (i < N_EDGES) {
        int d = dst[i];
        d = max(0, min(d, N_NODES - 1));
        atomicAdd(&cnt[d], 1);
    }
}

// ---------------- Kernel 2b: exclusive scan over counts (1 block) ----
__global__ __launch_bounds__(1024) void k_scan(const int* __restrict__ cnt,
                                               int* __restrict__ cursor) {
    __shared__ int tmp[1024];
    const int tid = threadIdx.x;
    int carry = 0;
    for (int base = 0; base < N_NODES; base += 1024) {
        int i = base + tid;
        int v = (i < N_NODES) ? cnt[i] : 0;
        tmp[tid] = v;
        __syncthreads();
        for (int off = 1; off < 1024; off <<= 1) {
            int t = (tid >= off) ? tmp[tid - off] : 0;
            __syncthreads();
            tmp[tid] += t;
            __syncthreads();
        }
        if (i < N_NODES) cursor[i] = carry + tmp[tid] - v;
        int tot = tmp[1023];
        __syncthreads();
        carry += tot;
    }
}

// ---------------- Kernel 2c: bucket placement -> dst-sorted edge ids ----
__global__ void k_place(const int* __restrict__ dst, int* __restrict__ cursor,
                        int* __restrict__ eorder) {
    int i = blockIdx.x * blockDim.x + threadIdx.x;
    if (i < N_EDGES) {
        int d = dst[i];
        d = max(0, min(d, N_NODES - 1));
        int pos = atomicAdd(&cursor[d], 1);
        pos = max(0, min(pos, N_EDGES - 1));
        eorder[pos] = i;
    }
}

// ---------------- Kernel 3: fused E-projection + score + segment-reduce ----
struct EdgeSmem {
    unsigned short Ae[64][TPAD];    // gathered e rows (bf16)
    unsigned short Wl[HD][TPAD];    // We rows (bf16)
    float bel[HD];
    float sc[64][NH];               // score_soft per edge/head
    int eids[64], srcs[64], dsts[64];
};

template<bool F32>
__device__ __forceinline__ void edge_body(
    EdgeSmem& sm,
    const void* __restrict__ e,
    const void* __restrict__ We, const void* __restrict__ be,
    const int* __restrict__ src, const int* __restrict__ dst,
    const int* __restrict__ eorder,
    const float* __restrict__ Qs, const float* __restrict__ Kg,
    const float* __restrict__ Vg,
    float* __restrict__ wV, float* __restrict__ zacc)
{
    const int tid = threadIdx.x;
    const int tile = blockIdx.x;

    if (tid < 64) {
        int eid = eorder[tile * 64 + tid];
        eid = max(0, min(eid, N_EDGES - 1));          // defensive clamp
        sm.eids[tid] = eid;
        int s = src[eid]; s = max(0, min(s, N_NODES - 1));
        int d = dst[eid]; d = max(0, min(d, N_NODES - 1));
        sm.srcs[tid] = s;
        sm.dsts[tid] = d;
    }
    if (tid < HD) sm.bel[tid] = ld1<F32>(be, tid);
    {   // stage We: thread -> row tid>>1, half tid&1 (64 elems)
        int row = tid >> 1, halfsel = tid & 1;
        uint4* lp = (uint4*)&sm.Wl[row][halfsel * 64];
        #pragma unroll
        for (int q = 0; q < 8; ++q)
            lp[q] = ld8b<F32>(We, (size_t)row * HD + halfsel * 64 + q * 8);
    }
    __syncthreads();
    {   // stage gathered e rows: thread -> row tid>>2, quarter tid&3 (32 elems)
        int row = tid >> 2, qq = tid & 3;
        size_t base = (size_t)sm.eids[row] * HD + qq * 32;
        uint4* lp = (uint4*)&sm.Ae[row][qq * 32];
        #pragma unroll
        for (int q = 0; q < 4; ++q)
            lp[q] = ld8b<F32>(e, base + q * 8);
    }
    __syncthreads();

    // ---- phase 1: per-wave 16 edges; loop heads; E stays in accumulators ----
    const int lane = tid & 63;
    const int w = tid >> 6;
    const int m0 = w * 16;
    const int col = lane & 15;
    const int lq = lane >> 4;

    for (int hh = 0; hh < NH; ++hh) {
        floatx4 acc = {0.f, 0.f, 0.f, 0.f};
        #pragma unroll
        for (int kt = 0; kt < 4; ++kt) {
            bf16x8 a = *(const bf16x8*)&sm.Ae[m0 + col][kt * 32 + lq * 8];
            bf16x8 b = *(const bf16x8*)&sm.Wl[hh * 16 + col][kt * 32 + lq * 8];
            acc = __builtin_amdgcn_mfma_f32_16x16x32_bf16(a, b, acc, 0, 0, 0);
        }
        float bev = sm.bel[hh * 16 + col];
        #pragma unroll
        for (int r = 0; r < 4; ++r) {
            int row = lq * 4 + r;
            int edge = m0 + row;
            int s_n = sm.srcs[edge], d_n = sm.dsts[edge];
            float kq = Kg[(size_t)s_n * HD + hh * 16 + col] *
                       Qs[(size_t)d_n * HD + hh * 16 + col];
            float p = (acc[r] + bev) * kq;
            p += __shfl_xor(p, 1);
            p += __shfl_xor(p, 2);
            p += __shfl_xor(p, 4);
            p += __shfl_xor(p, 8);
            if (col == 0) {
                p = fminf(fmaxf(p, -5.f), 5.f);
                sm.sc[edge][hh] = __expf(p);
            }
        }
    }
    __syncthreads();

    // ---- phase 2: segmented accumulation (edges sorted by dst) ----
    const int halfsel = tid >> 7;      // 0..1 -> 32 edges each
    const int hd = tid & 127;
    const int hhead = hd >> 4;
    const int e0 = halfsel * 32;

    float vv[32];
    #pragma unroll
    for (int i = 0; i < 32; ++i)
        vv[i] = Vg[(size_t)sm.srcs[e0 + i] * HD + hd];

    float accv = 0.f, accz = 0.f;
    int cur = sm.dsts[e0];
    #pragma unroll
    for (int i = 0; i < 32; ++i) {
        int ed = e0 + i;
        int dn = sm.dsts[ed];
        if (dn != cur) {               // wave-uniform branch
            atomicAdd(&wV[(size_t)cur * HD + hd], accv);
            if ((hd & 15) == 0) atomicAdd(&zacc[cur * NH + hhead], accz);
            accv = 0.f; accz = 0.f; cur = dn;
        }
        float s = sm.sc[ed][hhead];
        accv += s * vv[i];
        accz += s;
    }
    atomicAdd(&wV[(size_t)cur * HD + hd], accv);
    if ((hd & 15) == 0) atomicAdd(&zacc[cur * NH + hhead], accz);
}

__global__ __launch_bounds__(256) void k_edge(
    const void* e, const void* We, const void* be,
    const int* src, const int* dst, const int* eorder,
    const float* Qs, const float* Kg, const float* Vg,
    float* wV, float* zacc, const int* flag)
{
    __shared__ EdgeSmem sm;
    if (*flag) edge_body<true >(sm, e, We, be, src, dst, eorder, Qs, Kg, Vg, wV, zacc);
    else       edge_body<false>(sm, e, We, be, src, dst, eorder, Qs, Kg, Vg, wV, zacc);
}

// ---------------- Kernel 4: normalize + cast -------------------------------
// Output dtype follows input dtype: flag=1 -> fp32 out, flag=0 -> bf16 out.
__global__ void k_final(const float* __restrict__ wV, const float* __restrict__ zacc,
                        void* __restrict__ out, const int* __restrict__ flag) {
    int i = blockIdx.x * blockDim.x + threadIdx.x;
    if (i < N_NODES * HD) {
        int node = i >> 7;
        int hh = (i & 127) >> 4;
        float v = wV[i] / (zacc[node * NH + hh] + 1e-6f);
        if (*flag) ((float*)out)[i] = v;
        else       ((unsigned short*)out)[i] = f2b(v);
    }
}

extern "C" void kernel_launch(void* const* d_in, const int* in_sizes, int n_in,
                              void* d_out, int out_size, void* d_ws, size_t ws_size,
                              hipStream_t stream) {
    const void* h  = d_in[0];
    const void* e  = d_in[1];
    const int* src = (const int*)d_in[2];
    const int* dst = (const int*)d_in[3];
    const void* Wq = d_in[4];
    const void* bq = d_in[5];
    const void* Wk = d_in[6];
    const void* bk = d_in[7];
    const void* We = d_in[8];
    const void* be = d_in[9];
    const void* Wv = d_in[10];
    const void* bv = d_in[11];

    char* ws = (char*)d_ws;
    float* Qs    = (float*)(ws + 0);           //  5,120,000 B
    float* Kg    = (float*)(ws + 5120000);     //  5,120,000 B
    float* Vg    = (float*)(ws + 10240000);    //  5,120,000 B
    int* eorder  = (int*)  (ws + 15360000);    //  2,560,000 B
    int* cursor  = (int*)  (ws + 17920000);    //     40,000 B
    float* wV    = (float*)(ws + 17960000);    //  5,120,000 B (zeroed)
    float* zacc  = (float*)(ws + 23080000);    //    320,000 B (zeroed)
    int* cnt     = (int*)  (ws + 23400000);    //     40,000 B (zeroed)
    int* flag    = (int*)  (ws + 23440000);    //          4 B (zeroed)
    int* wcnt    = (int*)  (ws + 23440004);    //          4 B (zeroed)

    hipMemsetAsync(ws + 17960000, 0, 5480008, stream);

    k_sniff<<<1, 256, 0, stream>>>((const unsigned short*)h, wcnt, flag);
    k_qkv<<<N_NODES / 8, 128, 0, stream>>>(h, Wq, bq, Wk, bk, Wv, bv, Qs, Kg, Vg, flag);
    k_hist<<<(N_EDGES + 255) / 256, 256, 0, stream>>>(dst, cnt);
    k_scan<<<1, 1024, 0, stream>>>(cnt, cursor);
    k_place<<<(N_EDGES + 255) / 256, 256, 0, stream>>>(dst, cursor, eorder);
    k_edge<<<N_EDGES / 64, 256, 0, stream>>>(e, We, be, src, dst, eorder,
                                             Qs, Kg, Vg, wV, zacc, flag);
    k_final<<<(N_NODES * HD + 255) / 256, 256, 0, stream>>>(wV, zacc, d_out, flag);
}